// Round 1
// baseline (334.220 us; speedup 1.0000x reference)
//
#include <hip/hip_runtime.h>
#include <hip/hip_bf16.h>
#include <stdint.h>

// Problem constants (from reference): B=64, T=32, J=128, N=64, IN_F=4096, OUT_F=256
#define Bv   64
#define Tv   32
#define Jv   128
#define Nv   64
#define Lv   256
#define INFv 4096

typedef __attribute__((ext_vector_type(8))) short  short8;   // 8 bf16 (4 VGPRs) — MFMA A/B frag
typedef __attribute__((ext_vector_type(4))) float  floatx4;  // MFMA C/D frag

// f32 -> bf16 bits, round-to-nearest-even (inputs are finite normals)
__device__ __forceinline__ unsigned int f2bf(float f) {
  union { float f; unsigned int u; } v; v.f = f;
  unsigned int r = v.u + 0x7fffu + ((v.u >> 16) & 1u);
  return r >> 16;
}

// Kernel A: transpose+convert full_weight [256][4096] f32 -> Wt [4096][256] bf16.
// Reads: lane covers rows 4*lane..4*lane+3 (scalar, line-reused across r); writes
// coalesced 8B/lane (64 lanes = full 512B row of Wt).
__global__ __launch_bounds__(256) void wt_transpose_kernel(
    const float* __restrict__ w, unsigned short* __restrict__ wt) {
  int i_base = blockIdx.x * 16;      // 256 blocks x 16 i-values
  int wave = threadIdx.x >> 6;
  int lane = threadIdx.x & 63;
  #pragma unroll
  for (int r = 0; r < 4; ++r) {
    int i = i_base + wave * 4 + r;
    unsigned int b0 = f2bf(w[(size_t)(4 * lane + 0) * INFv + i]);
    unsigned int b1 = f2bf(w[(size_t)(4 * lane + 1) * INFv + i]);
    unsigned int b2 = f2bf(w[(size_t)(4 * lane + 2) * INFv + i]);
    unsigned int b3 = f2bf(w[(size_t)(4 * lane + 3) * INFv + i]);
    uint2 u;
    u.x = b0 | (b1 << 16);
    u.y = b2 | (b3 << 16);
    *(uint2*)(wt + (size_t)i * Lv + 4 * lane) = u;
  }
}

// Main kernel: one block per (b,t). Y[128x256] = X[128x64] @ G[64x256],
// G[n][l] = Wt[idx[n]][l]. LDS layout for both MFMA operands: [row][k], k fastest,
// XOR chunk swizzle: element (row,k) at row*64 + ((k>>3) ^ (row&7))*8 + (k&7).
// -> all b128 LDS reads/writes are 16B-aligned and bank-conflict-free.
__global__ __launch_bounds__(256, 2) void masklin_kernel(
    const float* __restrict__ x, const int* __restrict__ idx,
    const unsigned short* __restrict__ wt, const float* __restrict__ wfull,
    int use_wt, float* __restrict__ y) {
  __shared__ __align__(16) unsigned short lA[Jv * Nv];  // 16 KB: [j][k] swizzled
  __shared__ __align__(16) unsigned short lB[Lv * Nv];  // 32 KB: [l][k] swizzled
  __shared__ int idxs[Nv];

  int bt = blockIdx.x;               // 0..2047
  int b = bt >> 5, t = bt & 31;
  int tid = threadIdx.x;
  int wave = tid >> 6, lane = tid & 63;

  // indices[b][n][t], int32 per harness convention
  if (tid < Nv) idxs[tid] = idx[(b * Nv + tid) * Tv + t];

  // ---- stage A: X tile (128x64 f32, contiguous) -> bf16 swizzled LDS ----
  const float* xt = x + (size_t)(b * Tv + t) * (Jv * Nv);
  #pragma unroll
  for (int it = 0; it < 4; ++it) {
    int O = tid + it * 256;          // octet index: j = O>>3, chunk c = O&7
    int j = O >> 3, c = O & 7;
    const float4* p = (const float4*)(xt + (size_t)O * 8);
    float4 a0 = p[0], a1 = p[1];
    uint4 v;
    v.x = f2bf(a0.x) | (f2bf(a0.y) << 16);
    v.y = f2bf(a0.z) | (f2bf(a0.w) << 16);
    v.z = f2bf(a1.x) | (f2bf(a1.y) << 16);
    v.w = f2bf(a1.z) | (f2bf(a1.w) << 16);
    *(uint4*)&lA[j * 64 + ((c ^ (j & 7)) << 3)] = v;
  }
  __syncthreads();  // idxs visible to all; lA done

  // ---- stage B: gather G^T into lB[l][k=n] (transpose happens here) ----
  // thread owns column l = tid; inner loads are coalesced over l (2B * 64 lanes).
  {
    int l = tid;
    #pragma unroll
    for (int c = 0; c < 8; ++c) {
      unsigned int e[8];
      #pragma unroll
      for (int jj = 0; jj < 8; ++jj) {
        int n = c * 8 + jj;
        int in_row = idxs[n];
        if (use_wt) {
          e[jj] = wt[(size_t)in_row * Lv + l];
        } else {
          e[jj] = f2bf(wfull[(size_t)l * INFv + in_row]);  // fallback: no ws
        }
      }
      uint4 v;
      v.x = e[0] | (e[1] << 16);
      v.y = e[2] | (e[3] << 16);
      v.z = e[4] | (e[5] << 16);
      v.w = e[6] | (e[7] << 16);
      *(uint4*)&lB[l * 64 + ((c ^ (l & 7)) << 3)] = v;
    }
  }
  __syncthreads();

  // ---- MFMA: wave w computes rows 0..127 x cols [64w, 64w+64) ----
  int m = lane & 15, qd = lane >> 4;
  floatx4 acc[8][4];
  #pragma unroll
  for (int jt = 0; jt < 8; ++jt)
    #pragma unroll
    for (int lt = 0; lt < 4; ++lt)
      acc[jt][lt] = (floatx4){0.f, 0.f, 0.f, 0.f};

  #pragma unroll
  for (int ks = 0; ks < 2; ++ks) {
    int chunk = ks * 4 + qd;         // logical k-chunk = (ks*32 + qd*8) >> 3
    short8 afr[8], bfr[4];
    #pragma unroll
    for (int jt = 0; jt < 8; ++jt) {
      int j = jt * 16 + m;           // A[m=lane&15][k=qd*8+j]
      afr[jt] = *(const short8*)&lA[j * 64 + ((chunk ^ (j & 7)) << 3)];
    }
    #pragma unroll
    for (int lt = 0; lt < 4; ++lt) {
      int l = wave * 64 + lt * 16 + m;  // B[n=lane&15][k=qd*8+j]
      bfr[lt] = *(const short8*)&lB[l * 64 + ((chunk ^ (l & 7)) << 3)];
    }
    #pragma unroll
    for (int jt = 0; jt < 8; ++jt)
      #pragma unroll
      for (int lt = 0; lt < 4; ++lt)
        acc[jt][lt] = __builtin_amdgcn_mfma_f32_16x16x32_bf16(
            afr[jt], bfr[lt], acc[jt][lt], 0, 0, 0);
  }

  // ---- epilogue: C/D layout col=lane&15, row=qd*4+r; 16-lane groups write
  // 64B contiguous segments (full cachelines) ----
  float* yt = y + (size_t)(b * Tv + t) * (Jv * Lv);
  #pragma unroll
  for (int jt = 0; jt < 8; ++jt) {
    #pragma unroll
    for (int r = 0; r < 4; ++r) {
      int j = jt * 16 + qd * 4 + r;
      #pragma unroll
      for (int lt = 0; lt < 4; ++lt) {
        int l = wave * 64 + lt * 16 + m;
        yt[(size_t)j * Lv + l] = acc[jt][lt][r];
      }
    }
  }
}

extern "C" void kernel_launch(void* const* d_in, const int* in_sizes, int n_in,
                              void* d_out, int out_size, void* d_ws, size_t ws_size,
                              hipStream_t stream) {
  const float* x    = (const float*)d_in[0];
  const int*   idx  = (const int*)d_in[1];
  const float* w    = (const float*)d_in[2];
  float*       y    = (float*)d_out;

  const size_t wt_bytes = (size_t)INFv * Lv * sizeof(unsigned short);  // 2 MB
  int use_wt = (d_ws != nullptr && ws_size >= wt_bytes) ? 1 : 0;
  unsigned short* wt = (unsigned short*)d_ws;

  if (use_wt) {
    wt_transpose_kernel<<<256, 256, 0, stream>>>(w, wt);
  }
  masklin_kernel<<<Bv * Tv, 256, 0, stream>>>(x, idx, wt, w, use_wt, y);
}